// Round 12
// baseline (2845.427 us; speedup 1.0000x reference)
//
#include <hip/hip_runtime.h>

// SelfAttention: x[8,256,64,64] fp32, W[256,256] fp32.
// R12: R11 (fp8-MX QK, bf16 PV) + occupancy 2->4 blocks/CU:
// 4-way split-K (grid 1024 = 8b x 32qt x 4g, NT=32), LDS 32KB/block
// (K fp8 double-buffered 2x8KB, V bf16 SINGLE-buffered 16KB, 2 barriers/iter).
// __launch_bounds__(256,4) -> 4 waves/SIMD TLP. outgemm merges 4 partials.
// ws: xT8[b][N][C] fp8 | xC[b][C][N] bf16 | ctxP[4][b][N][C] | Wb | ML[4][b][N]

typedef __attribute__((ext_vector_type(8))) short short8;
typedef __attribute__((ext_vector_type(4))) float floatx4;
typedef __attribute__((ext_vector_type(16))) float floatx16;
typedef __attribute__((ext_vector_type(4))) int intx4;
typedef __attribute__((ext_vector_type(8))) int intx8;

#define N_TOK 4096
#define C_DIM 256
#define JT 32
#define NT 32  // 1024 / JT per quarter

typedef const __attribute__((address_space(1))) unsigned int g_uint;
typedef __attribute__((address_space(3))) unsigned int lds_uint;

__device__ __forceinline__ void gll16(const void* g, void* l) {
  __builtin_amdgcn_global_load_lds((g_uint*)g, (lds_uint*)l, 16, 0, 0);
}

__device__ __forceinline__ unsigned short f2bf(float f) {
  unsigned int u = __builtin_bit_cast(unsigned int, f);
  u += 0x7fffu + ((u >> 16) & 1u);
  return (unsigned short)(u >> 16);
}
__device__ __forceinline__ float bf2f(unsigned short v) {
  return __builtin_bit_cast(float, (unsigned int)v << 16);
}
// f32 -> fp8 e4m3fn, RNE, flush-subnormal, clamp 448 (hand-rolled)
__device__ __forceinline__ unsigned char f2f8(float f) {
  unsigned u = __builtin_bit_cast(unsigned, f);
  unsigned sgn = (u >> 24) & 0x80u;
  unsigned a = u & 0x7fffffffu;
  if (a > 0x43e40000u) return (unsigned char)(sgn | 0x7e);  // >456 -> 448
  unsigned lsb = (a >> 20) & 1u;
  a += 0x0007ffffu + lsb;  // RNE at 3-bit mantissa
  int e = (int)(a >> 23) - 127;
  if (e < -6) return (unsigned char)sgn;  // flush tiny/subnormal
  if (e > 8) return (unsigned char)(sgn | 0x7e);
  unsigned m = (a >> 20) & 7u;
  return (unsigned char)(sgn | ((unsigned)(e + 7) << 3) | m);
}

__device__ __forceinline__ floatx16 mfma32(short8 a, short8 b, floatx16 c) {
  return __builtin_amdgcn_mfma_f32_32x32x16_bf16(a, b, c, 0, 0, 0);
}
__device__ __forceinline__ floatx4 mfma16(short8 a, short8 b, floatx4 c) {
  return __builtin_amdgcn_mfma_f32_16x16x32_bf16(a, b, c, 0, 0, 0);
}
__device__ __forceinline__ floatx16 mfma_qk(intx8 a, intx8 b, floatx16 c) {
  // fp8 e4m3 A/B (cbsz=0, blgp=0), unity block scales (E8M0 127 = 2^0)
  return __builtin_amdgcn_mfma_scale_f32_32x32x64_f8f6f4(
      a, b, c, 0, 0, 0, 0x7f7f7f7f, 0, 0x7f7f7f7f);
}
__device__ __forceinline__ unsigned cvtpk(float lo, float hi) {
  unsigned d;
  asm("v_cvt_pk_bf16_f32 %0, %1, %2" : "=v"(d) : "v"(lo), "v"(hi));
  return d;
}
__device__ __forceinline__ void swap32(unsigned& a, unsigned& b) {
  asm("v_permlane32_swap_b32 %0, %1" : "+v"(a), "+v"(b));
}

// ---- K1a: x[b][c][i] fp32 -> xT8[b][i][c] fp8 and xC[b][c][i] bf16 ----
__global__ __launch_bounds__(256) void transpose_conv(
    const float* __restrict__ x, unsigned char* __restrict__ xT8,
    unsigned short* __restrict__ xC) {
  __shared__ float tile[32][33];
  const int b = blockIdx.z;
  const int i0 = blockIdx.x * 32, c0 = blockIdx.y * 32;
  const int tx = threadIdx.x & 31, ty = threadIdx.x >> 5;
  const float* xb = x + (size_t)b * C_DIM * N_TOK;
#pragma unroll
  for (int p = 0; p < 4; ++p) {
    int c = c0 + ty + p * 8;
    float v = xb[(size_t)c * N_TOK + i0 + tx];
    tile[ty + p * 8][tx] = v;
    xC[((size_t)b * C_DIM + c) * N_TOK + i0 + tx] = f2bf(v);
  }
  __syncthreads();
#pragma unroll
  for (int p = 0; p < 4; ++p) {
    int i = i0 + ty + p * 8;
    xT8[((size_t)b * N_TOK + i) * C_DIM + c0 + tx] = f2f8(tile[tx][ty + p * 8]);
  }
}

// ---- K1b: W fp32 -> bf16 ----
__global__ __launch_bounds__(256) void wconv(const float* __restrict__ W,
                                             unsigned short* __restrict__ Wb) {
  int idx = blockIdx.x * 256 + threadIdx.x;
  Wb[idx] = f2bf(W[idx]);
}

// ---- K2: split-K flash attention. grid 1024, 256 thr, 4 blocks/CU ----
// LDS: K fp8 double-buffered 2x8KB: elem(j,c16) at j*256 + ((c16^(j&15))<<4)
//      V bf16 single 16KB: paired rows [128r][128B]: elem(c,jc=j/8) at
//        (c>>1)*128 + (((jc | ((c&1)<<2)) ^ ((c>>1)&7))<<4)
__global__ __launch_bounds__(256, 4) void attn_kernel(
    const unsigned char* __restrict__ xT8, const unsigned short* __restrict__ xC,
    unsigned short* __restrict__ ctxP, float2* __restrict__ MLd) {
  const int bid = blockIdx.x;
  const int b = bid & 7;           // batch == XCD -> L2 locality
  const int qt = (bid >> 3) & 31;  // q-tile (128 rows)
  const int g = bid >> 8;          // j-quarter (0..3)
  const int tid = threadIdx.x;
  const int lane = tid & 63;
  const int wv = tid >> 6;
  const int l31 = lane & 31;
  const int h = lane >> 5;
  const unsigned char* xT8b = xT8 + (size_t)b * N_TOK * C_DIM;
  const unsigned short* xCb = xC + (size_t)b * N_TOK * C_DIM;
  const char* xT8c = (const char*)xT8b;
  const char* xCc = (const char*)xCb;
  const int qb = qt * 128 + wv * 32;

  __shared__ char ldsK[2][8192];
  __shared__ char ldsV[16384];

  // K staging: slots o = i*4096 + wv*1024 + lane*16 (i=0..1)
  //   j = i*16 + wv*4 + (lane>>4); c16 = (lane&15) ^ (j&15)
  auto STAGE_K = [&](int t, int sel) {
    size_t jb = (size_t)(g * 1024 + t * 32);
    char* Kd = ldsK[sel] + wv * 1024;
#pragma unroll
    for (int i = 0; i < 2; ++i) {
      int j = i * 16 + wv * 4 + (lane >> 4);
      int c16 = (lane & 15) ^ (j & 15);
      gll16(xT8c + (jb + j) * 256 + c16 * 16, Kd + i * 4096);
    }
  };
  // V staging (R5-proven layout), single buffer
  auto STAGE_V = [&](int t) {
    size_t jb = (size_t)(g * 1024 + t * 32);
    char* Vd = ldsV + wv * 1024;
#pragma unroll
    for (int i = 0; i < 4; ++i) {
      int r = i * 32 + wv * 8 + (lane >> 3);
      int e = (lane & 7) ^ (r & 7);
      int c = 2 * r + (e >> 2);
      gll16(xCc + (size_t)c * 8192 + jb * 2 + (e & 3) * 16, Vd + i * 4096);
    }
  };

  // Q fp8 B-fragments: row qb+l31, k-bytes c = ks*64 + h*32 + (0..31)
  intx8 q[4];
  {
    const unsigned char* qp = xT8b + (size_t)(qb + l31) * C_DIM + h * 32;
#pragma unroll
    for (int ks = 0; ks < 4; ++ks) {
      intx4 lo = *(const intx4*)(qp + ks * 64);
      intx4 hi = *(const intx4*)(qp + ks * 64 + 16);
      q[ks] = (intx8){lo.x, lo.y, lo.z, lo.w, hi.x, hi.y, hi.z, hi.w};
    }
  }

  floatx16 acc[8];
#pragma unroll
  for (int ct = 0; ct < 8; ++ct)
#pragma unroll
    for (int r = 0; r < 16; ++r) acc[ct][r] = 0.f;
  float m = -1e30f, lsum = 0.f;
  const float SC = 0.09016844005556021f;  // log2(e)/16

  STAGE_K(0, 0);

  for (int t = 0; t < NT; ++t) {
    __syncthreads();  // K(t) staged; all waves' PV(t-1) reads of V done
    STAGE_V(t);
    if (t + 1 < NT) STAGE_K(t + 1, (t + 1) & 1);
    const char* Kb = ldsK[t & 1];

    // S^T = mfma_scale(K8, Q8): A m=j=l31, B n=i=l31
    floatx16 s;
#pragma unroll
    for (int r = 0; r < 16; ++r) s[r] = 0.f;
    __builtin_amdgcn_s_setprio(1);
#pragma unroll
    for (int ks = 0; ks < 4; ++ks) {
      int ch = ((ks * 4 + h * 2) ^ (l31 & 15)) << 4;
      intx4 ka = *(const intx4*)(Kb + l31 * 256 + ch);
      intx4 kb2 = *(const intx4*)(Kb + l31 * 256 + (ch ^ 16));
      intx8 kf = (intx8){ka.x, ka.y, ka.z, ka.w, kb2.x, kb2.y, kb2.z, kb2.w};
      s = mfma_qk(kf, q[ks], s);
    }
    __builtin_amdgcn_s_setprio(0);

    // online softmax over 32 j (lane owns q-row i=l31; dup in h)
    float mx = s[0];
#pragma unroll
    for (int r = 1; r < 16; ++r) mx = fmaxf(mx, s[r]);
    mx = fmaxf(mx, __shfl_xor(mx, 32));
    float pm = mx * SC;
    bool need = __any(pm > m + 8.0f) != 0;  // defer-max (T13)
    float mn = need ? fmaxf(m, pm) : m;
    float al = need ? exp2f(m - mn) : 1.0f;
    m = mn;
    float rsum = 0.f;
#pragma unroll
    for (int r = 0; r < 16; ++r) {
      s[r] = exp2f(s[r] * SC - mn);
      rsum += s[r];
    }
    rsum += __shfl_xor(rsum, 32);
    lsum = lsum * al + rsum;
    if (need) {  // wave-uniform, rare after warmup
#pragma unroll
      for (int r = 0; r < 16; ++r) {
        float ar = __shfl(al, (r & 3) + 8 * (r >> 2) + 4 * h);
#pragma unroll
        for (int ct = 0; ct < 8; ++ct) acc[ct][r] *= ar;
      }
    }

    // P^T -> PV A-fragments in-register (cvt_pk + permlane32_swap), bf16
    unsigned pk[8];
#pragma unroll
    for (int pi = 0; pi < 8; ++pi) pk[pi] = cvtpk(s[2 * pi], s[2 * pi + 1]);
    swap32(pk[0], pk[2]); swap32(pk[1], pk[3]);
    swap32(pk[4], pk[6]); swap32(pk[5], pk[7]);
    intx4 a0v = {(int)pk[0], (int)pk[1], (int)pk[2], (int)pk[3]};
    intx4 a1v = {(int)pk[4], (int)pk[5], (int)pk[6], (int)pk[7]};
    short8 pa0 = __builtin_bit_cast(short8, a0v);  // k = j 0..15
    short8 pa1 = __builtin_bit_cast(short8, a1v);  // k = j 16..31

    __syncthreads();  // V(t) staged (barrier drains this wave's gll vmcnt)

    // O[i][c] += P[i][j] V[j][c]  (bf16, single V buffer)
    __builtin_amdgcn_s_setprio(1);
#pragma unroll
    for (int ct = 0; ct < 8; ++ct) {
      int c = ct * 32 + l31;
      int r = c >> 1;
      int pb = (c & 1) << 2;
      int r7 = r & 7;
      short8 v0 = *(const short8*)(ldsV + r * 128 + (((h | pb) ^ r7) << 4));
      short8 v1 = *(const short8*)(ldsV + r * 128 + ((((2 + h) | pb) ^ r7) << 4));
      acc[ct] = mfma32(pa0, v0, acc[ct]);
      acc[ct] = mfma32(pa1, v1, acc[ct]);
    }
    __builtin_amdgcn_s_setprio(0);
  }

  // epilogue: store partial O (bf16, unnormalized) + (m, l)
  if (h == 0) {
    float2 ml; ml.x = m; ml.y = lsum;
    MLd[((size_t)g * 8 + b) * N_TOK + qb + l31] = ml;
  }
  unsigned short* cb = ctxP + (((size_t)g * 8 + b) * N_TOK + qb) * C_DIM;
#pragma unroll
  for (int r = 0; r < 16; ++r) {
    int ri = (r & 3) + 8 * (r >> 2) + 4 * h;
#pragma unroll
    for (int ct = 0; ct < 8; ++ct)
      cb[(size_t)ri * C_DIM + ct * 32 + l31] = f2bf(acc[ct][r]);
  }
}

// ---- K3: merge 4 partials + out[b][o][i] = (1/l) sum_c W[o][c] ctx[i][c] ----
__global__ __launch_bounds__(256) void outgemm(
    const unsigned short* __restrict__ ctxP, const unsigned short* __restrict__ Wb,
    const float2* __restrict__ MLd, float* __restrict__ out) {
  const int bid = blockIdx.x;
  const int b = bid & 7;
  const int it = bid >> 3;
  const int lane = threadIdx.x & 63;
  const int w = threadIdx.x >> 6;
  const int ibase = it * 64 + w * 16;
  const int l15 = lane & 15, lhi = lane >> 4;

  const unsigned short* cbs[4];
#pragma unroll
  for (int gp = 0; gp < 4; ++gp)
    cbs[gp] = ctxP + (size_t)(gp * 8 + b) * N_TOK * C_DIM;

  // A-row merge weights (row ia = ibase + l15)
  const int ia = ibase + l15;
  float wk[4];
  {
    float2 ml[4];
    float Ma = -1e30f;
#pragma unroll
    for (int gp = 0; gp < 4; ++gp) {
      ml[gp] = MLd[(size_t)(gp * 8 + b) * N_TOK + ia];
      Ma = fmaxf(Ma, ml[gp].x);
    }
#pragma unroll
    for (int gp = 0; gp < 4; ++gp) wk[gp] = exp2f(ml[gp].x - Ma);
  }

  // store-row denominators (rows ibase + lhi*4 + r)
  float rden[4];
#pragma unroll
  for (int r = 0; r < 4; ++r) {
    int is = ibase + lhi * 4 + r;
    float2 ml[4];
    float Ms = -1e30f;
#pragma unroll
    for (int gp = 0; gp < 4; ++gp) {
      ml[gp] = MLd[(size_t)(gp * 8 + b) * N_TOK + is];
      Ms = fmaxf(Ms, ml[gp].x);
    }
    float den = 0.f;
#pragma unroll
    for (int gp = 0; gp < 4; ++gp) den += ml[gp].y * exp2f(ml[gp].x - Ms);
    rden[r] = 1.0f / den;
  }

  floatx4 acc[16];
#pragma unroll
  for (int i = 0; i < 16; ++i) acc[i] = (floatx4){0.f, 0.f, 0.f, 0.f};

#pragma unroll
  for (int ks = 0; ks < 8; ++ks) {
    short8 og[4];
#pragma unroll
    for (int gp = 0; gp < 4; ++gp)
      og[gp] = *(const short8*)(cbs[gp] + (size_t)ia * C_DIM + ks * 32 + lhi * 8);
    short8 am;
#pragma unroll
    for (int e = 0; e < 8; ++e) {
      float v = wk[0] * bf2f((unsigned short)og[0][e]) +
                wk[1] * bf2f((unsigned short)og[1][e]) +
                wk[2] * bf2f((unsigned short)og[2][e]) +
                wk[3] * bf2f((unsigned short)og[3][e]);
      am[e] = (short)f2bf(v);
    }
#pragma unroll
    for (int ob = 0; ob < 16; ++ob) {
      short8 bw = *(const short8*)(Wb + (size_t)(ob * 16 + l15) * C_DIM + ks * 32 + lhi * 8);
      acc[ob] = mfma16(am, bw, acc[ob]);
    }
  }
  float* outb = out + (size_t)b * C_DIM * N_TOK;
#pragma unroll
  for (int ob = 0; ob < 16; ++ob) {
#pragma unroll
    for (int r = 0; r < 4; ++r) {
      int o = ob * 16 + l15;
      int i = ibase + lhi * 4 + r;
      outb[(size_t)o * N_TOK + i] = acc[ob][r] * rden[r];
    }
  }
}

extern "C" void kernel_launch(void* const* d_in, const int* in_sizes, int n_in,
                              void* d_out, int out_size, void* d_ws, size_t ws_size,
                              hipStream_t stream) {
  const float* x = (const float*)d_in[0];
  const float* W = (const float*)d_in[1];
  float* out = (float*)d_out;
  char* ws = (char*)d_ws;
  const size_t SZ8 = (size_t)8 * N_TOK * C_DIM;      // 8 MB fp8 tensor
  const size_t SZ = SZ8 * 2;                         // 16 MB bf16 tensor
  unsigned char* xT8 = (unsigned char*)(ws);
  unsigned short* xC = (unsigned short*)(ws + SZ8);
  unsigned short* ctxP = (unsigned short*)(ws + SZ8 + SZ);        // 64 MB (4 quarters)
  unsigned short* Wb = (unsigned short*)(ws + SZ8 + 5 * SZ);      // 128 KB
  float2* MLd = (float2*)(ws + SZ8 + 5 * SZ + C_DIM * C_DIM * 2); // 1 MB

  hipLaunchKernelGGL(transpose_conv, dim3(N_TOK / 32, C_DIM / 32, 8), dim3(256), 0,
                     stream, x, xT8, xC);
  hipLaunchKernelGGL(wconv, dim3((C_DIM * C_DIM) / 256), dim3(256), 0, stream, W, Wb);
  hipLaunchKernelGGL(attn_kernel, dim3(1024), dim3(256), 0, stream, xT8, xC, ctxP, MLd);
  hipLaunchKernelGGL(outgemm, dim3(512), dim3(256), 0, stream, ctxP, Wb, MLd, out);
}

// Round 13
// 169.320 us; speedup vs baseline: 16.8050x; 16.8050x over previous
//
#include <hip/hip_runtime.h>

// SelfAttention: x[8,256,64,64] fp32, W[256,256] fp32.
// R13: R11 (fp8-MX QK + bf16 PV, 2 blocks/CU) + anti-phase stagger:
// the two co-resident blocks (g=0/g=1) are offset by ~half an iteration
// via one-time s_sleep, so their QK/softmax/PV phases interleave instead
// of lockstepping. Staging addresses hoisted to precomputed offsets.
// 512 blocks = 8b x 32qt x 2 j-halves; 4 waves x 32 q-rows; JT=32.
// ws: xT8[b][N][C] fp8 | xC[b][C][N] bf16 | ctxP[2][b][N][C] | Wb | ML

typedef __attribute__((ext_vector_type(8))) short short8;
typedef __attribute__((ext_vector_type(4))) float floatx4;
typedef __attribute__((ext_vector_type(16))) float floatx16;
typedef __attribute__((ext_vector_type(4))) int intx4;
typedef __attribute__((ext_vector_type(8))) int intx8;

#define N_TOK 4096
#define C_DIM 256
#define JT 32
#define NT 64  // 2048 / JT per half

typedef const __attribute__((address_space(1))) unsigned int g_uint;
typedef __attribute__((address_space(3))) unsigned int lds_uint;

__device__ __forceinline__ void gll16(const void* g, void* l) {
  __builtin_amdgcn_global_load_lds((g_uint*)g, (lds_uint*)l, 16, 0, 0);
}

__device__ __forceinline__ unsigned short f2bf(float f) {
  unsigned int u = __builtin_bit_cast(unsigned int, f);
  u += 0x7fffu + ((u >> 16) & 1u);
  return (unsigned short)(u >> 16);
}
__device__ __forceinline__ float bf2f(unsigned short v) {
  return __builtin_bit_cast(float, (unsigned int)v << 16);
}
// f32 -> fp8 e4m3fn, RNE, flush-subnormal, clamp 448 (hand-rolled)
__device__ __forceinline__ unsigned char f2f8(float f) {
  unsigned u = __builtin_bit_cast(unsigned, f);
  unsigned sgn = (u >> 24) & 0x80u;
  unsigned a = u & 0x7fffffffu;
  if (a > 0x43e40000u) return (unsigned char)(sgn | 0x7e);  // >456 -> 448
  unsigned lsb = (a >> 20) & 1u;
  a += 0x0007ffffu + lsb;  // RNE at 3-bit mantissa
  int e = (int)(a >> 23) - 127;
  if (e < -6) return (unsigned char)sgn;  // flush tiny/subnormal
  if (e > 8) return (unsigned char)(sgn | 0x7e);
  unsigned m = (a >> 20) & 7u;
  return (unsigned char)(sgn | ((unsigned)(e + 7) << 3) | m);
}

__device__ __forceinline__ floatx16 mfma32(short8 a, short8 b, floatx16 c) {
  return __builtin_amdgcn_mfma_f32_32x32x16_bf16(a, b, c, 0, 0, 0);
}
__device__ __forceinline__ floatx4 mfma16(short8 a, short8 b, floatx4 c) {
  return __builtin_amdgcn_mfma_f32_16x16x32_bf16(a, b, c, 0, 0, 0);
}
__device__ __forceinline__ floatx16 mfma_qk(intx8 a, intx8 b, floatx16 c) {
  // fp8 e4m3 A/B (cbsz=0, blgp=0), unity block scales (E8M0 127 = 2^0)
  return __builtin_amdgcn_mfma_scale_f32_32x32x64_f8f6f4(
      a, b, c, 0, 0, 0, 0x7f7f7f7f, 0, 0x7f7f7f7f);
}
__device__ __forceinline__ unsigned cvtpk(float lo, float hi) {
  unsigned d;
  asm("v_cvt_pk_bf16_f32 %0, %1, %2" : "=v"(d) : "v"(lo), "v"(hi));
  return d;
}
__device__ __forceinline__ void swap32(unsigned& a, unsigned& b) {
  asm("v_permlane32_swap_b32 %0, %1" : "+v"(a), "+v"(b));
}

// ---- K1a: x[b][c][i] fp32 -> xT8[b][i][c] fp8 and xC[b][c][i] bf16 ----
__global__ __launch_bounds__(256) void transpose_conv(
    const float* __restrict__ x, unsigned char* __restrict__ xT8,
    unsigned short* __restrict__ xC) {
  __shared__ float tile[32][33];
  const int b = blockIdx.z;
  const int i0 = blockIdx.x * 32, c0 = blockIdx.y * 32;
  const int tx = threadIdx.x & 31, ty = threadIdx.x >> 5;
  const float* xb = x + (size_t)b * C_DIM * N_TOK;
#pragma unroll
  for (int p = 0; p < 4; ++p) {
    int c = c0 + ty + p * 8;
    float v = xb[(size_t)c * N_TOK + i0 + tx];
    tile[ty + p * 8][tx] = v;
    xC[((size_t)b * C_DIM + c) * N_TOK + i0 + tx] = f2bf(v);
  }
  __syncthreads();
#pragma unroll
  for (int p = 0; p < 4; ++p) {
    int i = i0 + ty + p * 8;
    xT8[((size_t)b * N_TOK + i) * C_DIM + c0 + tx] = f2f8(tile[tx][ty + p * 8]);
  }
}

// ---- K1b: W fp32 -> bf16 ----
__global__ __launch_bounds__(256) void wconv(const float* __restrict__ W,
                                             unsigned short* __restrict__ Wb) {
  int idx = blockIdx.x * 256 + threadIdx.x;
  Wb[idx] = f2bf(W[idx]);
}

// ---- K2: split-K flash attention. grid 512, 256 thr, 2 blocks/CU ----
// LDS buffer (24KB each, x2):
//   K fp8 [0,8KB):  elem(j, c16=c/16) at j*256 + ((c16 ^ (j&15))<<4)
//   V bf16 [8KB,24KB): paired rows [128r][128B]: elem(c,jc=j/8) at
//                  (c>>1)*128 + (((jc | ((c&1)<<2)) ^ ((c>>1)&7))<<4)
__global__ __launch_bounds__(256, 2) void attn_kernel(
    const unsigned char* __restrict__ xT8, const unsigned short* __restrict__ xC,
    unsigned short* __restrict__ ctxP, float2* __restrict__ MLd) {
  const int bid = blockIdx.x;
  const int b = bid & 7;           // batch == XCD -> L2 locality
  const int qt = (bid >> 3) & 31;  // q-tile (128 rows)
  const int g = bid >> 8;          // j-half
  const int tid = threadIdx.x;
  const int lane = tid & 63;
  const int wv = tid >> 6;
  const int l31 = lane & 31;
  const int h = lane >> 5;
  const unsigned char* xT8b = xT8 + (size_t)b * N_TOK * C_DIM;
  const unsigned short* xCb = xC + (size_t)b * N_TOK * C_DIM;
  const int qb = qt * 128 + wv * 32;

  // anti-phase stagger: co-resident pair is (g=0, g=1); offset g=1 by
  // ~half an iteration (one-time) so their phases interleave, not lockstep
  if (g) { __builtin_amdgcn_s_sleep(15); __builtin_amdgcn_s_sleep(4); }

  __shared__ char lds[2][24576];

  // --- precomputed staging offsets (inverse-swizzled sources, rule #21) ---
  // K: slots o = i*4096 + wv*1024 + lane*16 (i=0..1)
  //    j = i*16 + wv*4 + (lane>>4); c16 = (lane&15) ^ (j&15)
  const char* kSrc[2];
  {
    const char* base = (const char*)xT8b + (size_t)g * 2048 * 256;
#pragma unroll
    for (int i = 0; i < 2; ++i) {
      int j = i * 16 + wv * 4 + (lane >> 4);
      int c16 = (lane & 15) ^ (j & 15);
      kSrc[i] = base + (size_t)j * 256 + c16 * 16;
    }
  }
  // V: slots o = i*4096 + wv*1024 + lane*16 (i=0..3), R5-proven layout
  const char* vSrc[4];
  {
    const char* base = (const char*)xCb + (size_t)g * 4096;
#pragma unroll
    for (int i = 0; i < 4; ++i) {
      int r = i * 32 + wv * 8 + (lane >> 3);
      int e = (lane & 7) ^ (r & 7);
      int c = 2 * r + (e >> 2);
      vSrc[i] = base + (size_t)c * 8192 + (e & 3) * 16;
    }
  }
  auto STAGE_K = [&](int t, int sel) {
    char* Kd = lds[sel] + wv * 1024;
    size_t toff = (size_t)t * 8192;  // 32 rows * 256 B
#pragma unroll
    for (int i = 0; i < 2; ++i) gll16(kSrc[i] + toff, Kd + i * 4096);
  };
  auto STAGE_V = [&](int t, int sel) {
    char* Vd = lds[sel] + 8192 + wv * 1024;
    size_t toff = (size_t)t * 64;  // 32 j * 2 B within xC rows
#pragma unroll
    for (int i = 0; i < 4; ++i) gll16(vSrc[i] + toff, Vd + i * 4096);
  };

  // Q fp8 B-fragments: row qb+l31, k-bytes c = ks*64 + h*32 + (0..31)
  intx8 q[4];
  {
    const unsigned char* qp = xT8b + (size_t)(qb + l31) * C_DIM + h * 32;
#pragma unroll
    for (int ks = 0; ks < 4; ++ks) {
      intx4 lo = *(const intx4*)(qp + ks * 64);
      intx4 hi = *(const intx4*)(qp + ks * 64 + 16);
      q[ks] = (intx8){lo.x, lo.y, lo.z, lo.w, hi.x, hi.y, hi.z, hi.w};
    }
  }

  floatx16 acc[8];
#pragma unroll
  for (int ct = 0; ct < 8; ++ct)
#pragma unroll
    for (int r = 0; r < 16; ++r) acc[ct][r] = 0.f;
  float m = -1e30f, lsum = 0.f;
  const float SC = 0.09016844005556021f;  // log2(e)/16

  STAGE_K(0, 0);
  STAGE_V(0, 0);

  for (int t = 0; t < NT; ++t) {
    __syncthreads();  // tile t staged (vmcnt drain); prev-buf reads done
    if (t + 1 < NT) {
      STAGE_K(t + 1, (t + 1) & 1);
      STAGE_V(t + 1, (t + 1) & 1);
    }
    const char* Kb = lds[t & 1];
    const char* Vb = lds[t & 1] + 8192;

    // S^T = mfma_scale(K8, Q8): A m=j=l31, B n=i=l31
    floatx16 s;
#pragma unroll
    for (int r = 0; r < 16; ++r) s[r] = 0.f;
    __builtin_amdgcn_s_setprio(1);
#pragma unroll
    for (int ks = 0; ks < 4; ++ks) {
      int ch = ((ks * 4 + h * 2) ^ (l31 & 15)) << 4;
      intx4 ka = *(const intx4*)(Kb + l31 * 256 + ch);
      intx4 kb2 = *(const intx4*)(Kb + l31 * 256 + (ch ^ 16));
      intx8 kf = (intx8){ka.x, ka.y, ka.z, ka.w, kb2.x, kb2.y, kb2.z, kb2.w};
      s = mfma_qk(kf, q[ks], s);
    }
    __builtin_amdgcn_s_setprio(0);

    // online softmax over 32 j (lane owns q-row i=l31; dup in h)
    float mx = s[0];
#pragma unroll
    for (int r = 1; r < 16; ++r) mx = fmaxf(mx, s[r]);
    mx = fmaxf(mx, __shfl_xor(mx, 32));
    float pm = mx * SC;
    bool need = __any(pm > m + 8.0f) != 0;  // defer-max (T13)
    float mn = need ? fmaxf(m, pm) : m;
    float al = need ? exp2f(m - mn) : 1.0f;
    m = mn;
    float rsum = 0.f;
#pragma unroll
    for (int r = 0; r < 16; ++r) {
      s[r] = exp2f(s[r] * SC - mn);
      rsum += s[r];
    }
    rsum += __shfl_xor(rsum, 32);
    lsum = lsum * al + rsum;
    if (need) {  // wave-uniform, rare after warmup
#pragma unroll
      for (int r = 0; r < 16; ++r) {
        float ar = __shfl(al, (r & 3) + 8 * (r >> 2) + 4 * h);
#pragma unroll
        for (int ct = 0; ct < 8; ++ct) acc[ct][r] *= ar;
      }
    }

    // P^T -> PV A-fragments in-register (cvt_pk + permlane32_swap), bf16
    unsigned pk[8];
#pragma unroll
    for (int pi = 0; pi < 8; ++pi) pk[pi] = cvtpk(s[2 * pi], s[2 * pi + 1]);
    swap32(pk[0], pk[2]); swap32(pk[1], pk[3]);
    swap32(pk[4], pk[6]); swap32(pk[5], pk[7]);
    intx4 a0v = {(int)pk[0], (int)pk[1], (int)pk[2], (int)pk[3]};
    intx4 a1v = {(int)pk[4], (int)pk[5], (int)pk[6], (int)pk[7]};
    short8 pa0 = __builtin_bit_cast(short8, a0v);  // k = j 0..15
    short8 pa1 = __builtin_bit_cast(short8, a1v);  // k = j 16..31

    // O[i][c] += P[i][j] V[j][c]  (bf16, R5-proven path)
    __builtin_amdgcn_s_setprio(1);
#pragma unroll
    for (int ct = 0; ct < 8; ++ct) {
      int c = ct * 32 + l31;
      int r = c >> 1;
      int pb = (c & 1) << 2;
      int r7 = r & 7;
      short8 v0 = *(const short8*)(Vb + r * 128 + (((h | pb) ^ r7) << 4));
      short8 v1 = *(const short8*)(Vb + r * 128 + ((((2 + h) | pb) ^ r7) << 4));
      acc[ct] = mfma32(pa0, v0, acc[ct]);
      acc[ct] = mfma32(pa1, v1, acc[ct]);
    }
    __builtin_amdgcn_s_setprio(0);
  }

  // epilogue: store partial O (bf16, unnormalized) + (m, l)
  if (h == 0) {
    float2 ml; ml.x = m; ml.y = lsum;
    MLd[((size_t)g * 8 + b) * N_TOK + qb + l31] = ml;
  }
  unsigned short* cb = ctxP + (((size_t)g * 8 + b) * N_TOK + qb) * C_DIM;
#pragma unroll
  for (int r = 0; r < 16; ++r) {
    int ri = (r & 3) + 8 * (r >> 2) + 4 * h;
#pragma unroll
    for (int ct = 0; ct < 8; ++ct)
      cb[(size_t)ri * C_DIM + ct * 32 + l31] = f2bf(acc[ct][r]);
  }
}

// ---- K3: merge halves + out[b][o][i] = (1/l) sum_c W[o][c] ctx[i][c] ----
__global__ __launch_bounds__(256) void outgemm(
    const unsigned short* __restrict__ ctxP, const unsigned short* __restrict__ Wb,
    const float2* __restrict__ MLd, float* __restrict__ out) {
  const int bid = blockIdx.x;
  const int b = bid & 7;
  const int it = bid >> 3;
  const int lane = threadIdx.x & 63;
  const int w = threadIdx.x >> 6;
  const int ibase = it * 64 + w * 16;
  const int l15 = lane & 15, lhi = lane >> 4;
  const unsigned short* c0base = ctxP + (size_t)b * N_TOK * C_DIM;
  const unsigned short* c1base = ctxP + (size_t)(8 + b) * N_TOK * C_DIM;
  const float2* ml0b = MLd + (size_t)b * N_TOK;
  const float2* ml1b = MLd + (size_t)(8 + b) * N_TOK;

  // A-row merge weights (row ia = ibase + l15)
  const int ia = ibase + l15;
  float2 ma = ml0b[ia], mb = ml1b[ia];
  float Ma = fmaxf(ma.x, mb.x);
  float w0 = exp2f(ma.x - Ma), w1 = exp2f(mb.x - Ma);

  // store-row denominators (rows ibase + lhi*4 + r)
  float rden[4];
#pragma unroll
  for (int r = 0; r < 4; ++r) {
    int is = ibase + lhi * 4 + r;
    float2 s0 = ml0b[is], s1 = ml1b[is];
    float Ms = fmaxf(s0.x, s1.x);
    rden[r] = 1.0f / (s0.y * exp2f(s0.x - Ms) + s1.y * exp2f(s1.x - Ms));
  }

  floatx4 acc[16];
#pragma unroll
  for (int i = 0; i < 16; ++i) acc[i] = (floatx4){0.f, 0.f, 0.f, 0.f};

#pragma unroll
  for (int ks = 0; ks < 8; ++ks) {
    short8 o0 = *(const short8*)(c0base + (size_t)ia * C_DIM + ks * 32 + lhi * 8);
    short8 o1 = *(const short8*)(c1base + (size_t)ia * C_DIM + ks * 32 + lhi * 8);
    short8 am;
#pragma unroll
    for (int e = 0; e < 8; ++e)
      am[e] = (short)f2bf(w0 * bf2f((unsigned short)o0[e]) +
                          w1 * bf2f((unsigned short)o1[e]));
#pragma unroll
    for (int ob = 0; ob < 16; ++ob) {
      short8 bw = *(const short8*)(Wb + (size_t)(ob * 16 + l15) * C_DIM + ks * 32 + lhi * 8);
      acc[ob] = mfma16(am, bw, acc[ob]);
    }
  }
  float* outb = out + (size_t)b * C_DIM * N_TOK;
#pragma unroll
  for (int ob = 0; ob < 16; ++ob) {
#pragma unroll
    for (int r = 0; r < 4; ++r) {
      int o = ob * 16 + l15;
      int i = ibase + lhi * 4 + r;
      outb[(size_t)o * N_TOK + i] = acc[ob][r] * rden[r];
    }
  }
}

extern "C" void kernel_launch(void* const* d_in, const int* in_sizes, int n_in,
                              void* d_out, int out_size, void* d_ws, size_t ws_size,
                              hipStream_t stream) {
  const float* x = (const float*)d_in[0];
  const float* W = (const float*)d_in[1];
  float* out = (float*)d_out;
  char* ws = (char*)d_ws;
  const size_t SZ8 = (size_t)8 * N_TOK * C_DIM;      // 8 MB fp8 tensor
  const size_t SZ = SZ8 * 2;                         // 16 MB bf16 tensor
  unsigned char* xT8 = (unsigned char*)(ws);
  unsigned short* xC = (unsigned short*)(ws + SZ8);
  unsigned short* ctxP = (unsigned short*)(ws + SZ8 + SZ);        // 32 MB (2 halves)
  unsigned short* Wb = (unsigned short*)(ws + SZ8 + 3 * SZ);      // 128 KB
  float2* MLd = (float2*)(ws + SZ8 + 3 * SZ + C_DIM * C_DIM * 2); // 512 KB

  hipLaunchKernelGGL(transpose_conv, dim3(N_TOK / 32, C_DIM / 32, 8), dim3(256), 0,
                     stream, x, xT8, xC);
  hipLaunchKernelGGL(wconv, dim3((C_DIM * C_DIM) / 256), dim3(256), 0, stream, W, Wb);
  hipLaunchKernelGGL(attn_kernel, dim3(512), dim3(256), 0, stream, xT8, xC, ctxP, MLd);
  hipLaunchKernelGGL(outgemm, dim3(512), dim3(256), 0, stream, ctxP, Wb, MLd, out);
}